// Round 10
// baseline (916.210 us; speedup 1.0000x reference)
//
#include <hip/hip_runtime.h>
#include <stdint.h>

typedef __attribute__((ext_vector_type(8))) short bf8_t;   // 8 bf16 (4 VGPRs) MFMA A/B frag
typedef __attribute__((ext_vector_type(4))) float f4_t;    // MFMA C/D frag

#define DEVI static __device__ __forceinline__

// fp32 -> bf16 round-to-nearest-even
DEVI unsigned short f2b(float f) {
  unsigned u = __builtin_bit_cast(unsigned, f);
  u += 0x7fffu + ((u >> 16) & 1u);
  return (unsigned short)(u >> 16);
}

DEVI float b2f(unsigned short v) {
  return __builtin_bit_cast(float, (unsigned)v << 16);
}

// ---------------------------------------------------------------- cast kernel (with optional scale fold)
__global__ void cast_bf16_k(const float* __restrict__ src, ushort* __restrict__ dst, int n4, float scale) {
  int i = blockIdx.x * 256 + threadIdx.x;
  if (i >= n4) return;
  float4 v = reinterpret_cast<const float4*>(src)[i];
  ushort4 o;
  o.x = f2b(v.x * scale); o.y = f2b(v.y * scale); o.z = f2b(v.z * scale); o.w = f2b(v.w * scale);
  reinterpret_cast<ushort4*>(dst)[i] = o;
}

// ---------------------------------------------------------------- mask bit-pack
// mask int32 (b,n,m) in {0,1}  ->  packed ushort words: word i covers cols i*16..i*16+15,
// bit j = mask[col i*16+j]. Total 4*2048*128 ushorts = 2 MB (L2-resident in attn).
__global__ void mask_pack_k(const int* __restrict__ mask, ushort* __restrict__ mp, int nwords) {
  int i = blockIdx.x * 256 + threadIdx.x;
  if (i >= nwords) return;
  const int4* src = reinterpret_cast<const int4*>(mask + (size_t)i * 16);
  unsigned v = 0;
#pragma unroll
  for (int j = 0; j < 4; j++) {
    int4 m = src[j];
    v |= ((unsigned)(m.x & 1) << (j * 4 + 0));
    v |= ((unsigned)(m.y & 1) << (j * 4 + 1));
    v |= ((unsigned)(m.z & 1) << (j * 4 + 2));
    v |= ((unsigned)(m.w & 1) << (j * 4 + 3));
  }
  mp[i] = (ushort)v;
}

// ---------------------------------------------------------------- GEMM: C[n][o] = sum_d A[n][d]*W[o][d] + bias[o]*bscale
template<int MODE>
__global__ __launch_bounds__(256, 3) void gemm_bt(const ushort* __restrict__ A,
                                                  const ushort* __restrict__ W,
                                                  const float* __restrict__ bias,
                                                  void* __restrict__ outp, float bscale) {
  // XOR-swizzled LDS tiles: row stride 64 bf16 (128B), unit (16B) u stored at u ^ (row&7)
  __shared__ ushort As[128 * 64];
  __shared__ ushort Ws[128 * 64];
  const int t = threadIdx.x;
  const int tileCol = blockIdx.x & 7;
  const int tileRow = blockIdx.x >> 3;
  const int rowBase = tileRow * 128;
  const int colBase = tileCol * 128;

  const int r32 = t >> 3;
  const int cu = t & 7;
  const int w = t >> 6;
  const int lane = t & 63;
  const int q = lane >> 4;
  const int c = lane & 15;
  const int wr = (w >> 1) * 64;
  const int wc = (w & 1) * 64;

  f4_t acc[4][4];
#pragma unroll
  for (int i = 0; i < 4; i++)
#pragma unroll
    for (int j = 0; j < 4; j++) acc[i][j] = (f4_t){0.f, 0.f, 0.f, 0.f};

  for (int k0 = 0; k0 < 1024; k0 += 64) {
#pragma unroll
    for (int rs = 0; rs < 4; rs++) {
      int r = rs * 32 + r32;
      int4 va = *reinterpret_cast<const int4*>(A + (size_t)(rowBase + r) * 1024 + k0 + cu * 8);
      int4 vw = *reinterpret_cast<const int4*>(W + (size_t)(colBase + r) * 1024 + k0 + cu * 8);
      *reinterpret_cast<int4*>(&As[r * 64 + ((cu ^ (r & 7)) << 3)]) = va;
      *reinterpret_cast<int4*>(&Ws[r * 64 + ((cu ^ (r & 7)) << 3)]) = vw;
    }
    __syncthreads();
    bf8_t af[4][2], bfr[4][2];
#pragma unroll
    for (int i = 0; i < 4; i++) {
      int ra = wr + i * 16 + c;
      int rb = wc + i * 16 + c;
#pragma unroll
      for (int s = 0; s < 2; s++) {
        af[i][s] = *reinterpret_cast<const bf8_t*>(&As[ra * 64 + (((s * 4 + q) ^ (ra & 7)) << 3)]);
        bfr[i][s] = *reinterpret_cast<const bf8_t*>(&Ws[rb * 64 + (((s * 4 + q) ^ (rb & 7)) << 3)]);
      }
    }
#pragma unroll
    for (int i = 0; i < 4; i++)
#pragma unroll
      for (int j = 0; j < 4; j++) {
        acc[i][j] = __builtin_amdgcn_mfma_f32_16x16x32_bf16(af[i][0], bfr[j][0], acc[i][j], 0, 0, 0);
        acc[i][j] = __builtin_amdgcn_mfma_f32_16x16x32_bf16(af[i][1], bfr[j][1], acc[i][j], 0, 0, 0);
      }
    __syncthreads();
  }

  // epilogue: D layout col=lane&15, row=(lane>>4)*4+reg  [measured m89/m91]
#pragma unroll
  for (int j = 0; j < 4; j++) {
    int col = colBase + wc + j * 16 + c;
    float bj = bias[col] * bscale;
#pragma unroll
    for (int i = 0; i < 4; i++) {
      int rbase = rowBase + wr + i * 16 + q * 4;
      if (MODE == 0) {
        ushort* out = (ushort*)outp;
#pragma unroll
        for (int reg = 0; reg < 4; reg++)
          out[(size_t)(rbase + reg) * 1024 + col] = f2b(acc[i][j][reg] + bj);
      } else if (MODE == 1) {
        ushort* out = (ushort*)outp;
        int bb = rbase >> 11;
        int nl = rbase & 2047;
        ushort4 v;
        v.x = f2b(acc[i][j][0] + bj);
        v.y = f2b(acc[i][j][1] + bj);
        v.z = f2b(acc[i][j][2] + bj);
        v.w = f2b(acc[i][j][3] + bj);
        *reinterpret_cast<ushort4*>(out + ((size_t)(bb * 1024 + col) * 2048 + nl)) = v;
      } else {
        float* out = (float*)outp;
#pragma unroll
        for (int reg = 0; reg < 4; reg++)
          out[(size_t)(rbase + reg) * 1024 + col] = acc[i][j][reg] + bj;
      }
    }
  }
}

// ---------------------------------------------------------------- fused attention: P in LDS, 16 waves
// Block: one (b,h), 16 q-rows, 1024 threads; 16 waves x 128-col m-strips.
// Q PRE-SCALED by (1/sqrt(64))*log2(e) -> exp2(s) is the softmax numerator.
// R8 structure (sweep -> barrier -> PV+beta -> barrier -> merge) kept verbatim; R9 showed
// PV-fusion is not a win. This round attacks the measured stall: blocks were ~95% idle at
// 16 waves/CU (50% occupancy). 1024-thread blocks halve each wave's serial chunk chain
// (8 chunks) and put 32 waves/CU in flight (2 blocks x 16 waves; LDS 70KB/block; VGPR
// pinned <=64 by __launch_bounds__(1024,8), the count R8 measured). Latency-bound kernel
// + 2x resident waves + half-length chains => ~2x on the stall fraction.
__global__ __launch_bounds__(1024, 8) void attn_k(const ushort* __restrict__ Qb,
                                                  const ushort* __restrict__ Kb,
                                                  const ushort* __restrict__ Vt,
                                                  const ushort* __restrict__ Mp,
                                                  float* __restrict__ beta,
                                                  ushort* __restrict__ Cc) {
  __shared__ float OwU[16][16][68];   // 69632B; unioned with P strips (P = 65536B)
  __shared__ float lpart[16][16];
  ushort* Pl = (ushort*)OwU;          // 16 strips x [16 rows][128 cols], 16B-unit swizzled

  // XCD-affine swizzle: head-pairs pinned to XCD so K/V stay L2-resident
  const int L = blockIdx.x;
  const int bh = (L >> 10) * 8 + (L & 7);  // 0..63
  const int qt = (L >> 3) & 127;
  const int b = bh >> 4;
  const int h = bh & 15;
  const int n0 = qt * 16;

  const int t = threadIdx.x;
  const int w = t >> 6;    // 0..15
  const int lane = t & 63;
  const int q = lane >> 4;
  const int c = lane & 15;

  const size_t qbase = ((size_t)(b * 2048 + n0 + c)) * 1024 + h * 64 + q * 8;
  bf8_t qa0 = *reinterpret_cast<const bf8_t*>(Qb + qbase);
  bf8_t qa1 = *reinterpret_cast<const bf8_t*>(Qb + qbase + 32);

  const int mBase = w * 128;
  const size_t kbase0 = ((size_t)(b * 2048 + mBase + c)) * 1024 + h * 64 + q * 8;
  const size_t vbase = ((size_t)(b * 1024 + h * 64 + c)) * 2048 + mBase + q * 8;
  const ushort* mpk = Mp + ((size_t)(b * 2048 + n0)) * 128 + (mBase >> 4);
  ushort* Ps = Pl + w * (16 * 128);  // this wave's strip

  // ---- pass 1: QK sweep (8 chunks), e -> LDS strip, accumulate l
  float ls[4] = {0.f, 0.f, 0.f, 0.f};
#pragma unroll 2
  for (int mb = 0; mb < 8; ++mb) {
    const ushort* kp = Kb + kbase0 + (size_t)mb * 16 * 1024;
    bf8_t k0 = *reinterpret_cast<const bf8_t*>(kp);
    bf8_t k1 = *reinterpret_cast<const bf8_t*>(kp + 32);
    f4_t s = (f4_t){0.f, 0.f, 0.f, 0.f};
    s = __builtin_amdgcn_mfma_f32_16x16x32_bf16(qa0, k0, s, 0, 0, 0);
    s = __builtin_amdgcn_mfma_f32_16x16x32_bf16(qa1, k1, s, 0, 0, 0);
    const int u = mb * 2 + (c >> 3);
#pragma unroll
    for (int reg = 0; reg < 4; reg++) {
      const int row = q * 4 + reg;
      unsigned mw = mpk[(size_t)row * 128 + mb];  // broadcast across 16 lanes
      float e = ((mw >> c) & 1u) ? 0.f : __builtin_amdgcn_exp2f(s[reg]);
      ls[reg] += e;
      Ps[row * 128 + (((u ^ (row & 7)) << 3) | (c & 7))] = f2b(e);
    }
  }

  // ---- l reduce -> lpart
#pragma unroll
  for (int reg = 0; reg < 4; reg++) {
    ls[reg] += __shfl_xor(ls[reg], 1);
    ls[reg] += __shfl_xor(ls[reg], 2);
    ls[reg] += __shfl_xor(ls[reg], 4);
    ls[reg] += __shfl_xor(ls[reg], 8);
  }
  if (c == 0) {
#pragma unroll
    for (int reg = 0; reg < 4; reg++) lpart[w][q * 4 + reg] = ls[reg];
  }
  __syncthreads();  // P strips + lpart visible to all

  // ---- pass 2a: PV from own LDS strip (unnormalized); V loads free to pipeline
  f4_t o[4];
#pragma unroll
  for (int db = 0; db < 4; db++) o[db] = (f4_t){0.f, 0.f, 0.f, 0.f};
#pragma unroll 2
  for (int p = 0; p < 4; ++p) {
    const int uu = p * 4 + q;
    bf8_t pa = *reinterpret_cast<const bf8_t*>(&Ps[c * 128 + ((uu ^ (c & 7)) << 3)]);
    const int m0 = p * 32;
#pragma unroll
    for (int db = 0; db < 4; db++) {
      bf8_t vf = *reinterpret_cast<const bf8_t*>(Vt + vbase + (size_t)db * 16 * 2048 + m0);
      o[db] = __builtin_amdgcn_mfma_f32_16x16x32_bf16(pa, vf, o[db], 0, 0, 0);
    }
  }

  // ---- pass 2b: beta = P * (1/l): thread t -> row r=t>>6, col-block j=t&63 (32 cols each)
  {
    const int r = t >> 6;
    const int j = t & 63;
    float lsum = 0.f;
#pragma unroll
    for (int ww = 0; ww < 16; ww++) lsum += lpart[ww][r];
    const float li = 1.0f / lsum;
    float* brow = beta + ((size_t)(bh * 2048 + n0 + r)) * 2048;
    const int strip = j >> 2;
#pragma unroll
    for (int ii = 0; ii < 4; ++ii) {
      const int u = (j & 3) * 4 + ii;  // unit within strip (0..15)
      bf8_t pv = *reinterpret_cast<const bf8_t*>(&Pl[strip * 2048 + r * 128 + ((u ^ (r & 7)) << 3)]);
      float4 f0, f1;
      f0.x = b2f((unsigned short)pv[0]) * li;
      f0.y = b2f((unsigned short)pv[1]) * li;
      f0.z = b2f((unsigned short)pv[2]) * li;
      f0.w = b2f((unsigned short)pv[3]) * li;
      f1.x = b2f((unsigned short)pv[4]) * li;
      f1.y = b2f((unsigned short)pv[5]) * li;
      f1.z = b2f((unsigned short)pv[6]) * li;
      f1.w = b2f((unsigned short)pv[7]) * li;
      float* dst = brow + strip * 128 + u * 8;
      *reinterpret_cast<float4*>(dst) = f0;
      *reinterpret_cast<float4*>(dst + 4) = f1;
    }
  }

  __syncthreads();  // all P reads (PV + beta) done -> safe to overwrite with Ow

  // ---- merge O across 16 waves via union region, scale by 1/l, store concat bf16
#pragma unroll
  for (int db = 0; db < 4; db++)
#pragma unroll
    for (int reg = 0; reg < 4; reg++)
      OwU[w][q * 4 + reg][db * 16 + c] = o[db][reg];
  __syncthreads();
  if (t < 256) {
    int r = t >> 4;
    int d0 = (t & 15) * 4;
    float lsum = 0.f;
#pragma unroll
    for (int ww = 0; ww < 16; ww++) lsum += lpart[ww][r];
    float sl = 1.0f / lsum;
    float4 acc = (float4){0.f, 0.f, 0.f, 0.f};
#pragma unroll
    for (int ww = 0; ww < 16; ww++) {
      float4 sv = *reinterpret_cast<const float4*>(&OwU[ww][r][d0]);
      acc.x += sv.x; acc.y += sv.y; acc.z += sv.z; acc.w += sv.w;
    }
    ushort4 ov;
    ov.x = f2b(acc.x * sl);
    ov.y = f2b(acc.y * sl);
    ov.z = f2b(acc.z * sl);
    ov.w = f2b(acc.w * sl);
    *reinterpret_cast<ushort4*>(Cc + ((size_t)(b * 2048 + n0 + r)) * 1024 + h * 64 + d0) = ov;
  }
}

// ---------------------------------------------------------------- launch
extern "C" void kernel_launch(void* const* d_in, const int* in_sizes, int n_in,
                              void* d_out, int out_size, void* d_ws, size_t ws_size,
                              hipStream_t stream) {
  (void)in_sizes; (void)n_in; (void)out_size; (void)ws_size;
  const float* X = (const float*)d_in[0];
  const float* Y = (const float*)d_in[1];
  const int* mask = (const int*)d_in[2];
  const float* Wq = (const float*)d_in[3];
  const float* bq = (const float*)d_in[4];
  const float* Wk = (const float*)d_in[5];
  const float* bk = (const float*)d_in[6];
  const float* Wv = (const float*)d_in[7];
  const float* bv = (const float*)d_in[8];
  const float* Wo = (const float*)d_in[9];
  const float* bo = (const float*)d_in[10];
  float* out = (float*)d_out;

  const float SC = 0.18033688011112042f;  // (1/sqrt(64)) * log2(e), folded into Wq/bq

  char* ws = (char*)d_ws;
  const size_t SZ = 16777216;  // 8192*1024*2B
  ushort* Xb = (ushort*)(ws);
  ushort* Yb = (ushort*)(ws + SZ);
  ushort* Qb = (ushort*)(ws + 2 * SZ);
  ushort* Kb = (ushort*)(ws + 3 * SZ);
  ushort* Vt = (ushort*)(ws + 4 * SZ);
  ushort* Cc = (ushort*)(ws + 5 * SZ);
  ushort* Wqb = (ushort*)(ws + 6 * SZ);
  ushort* Wkb = (ushort*)(ws + 6 * SZ + 2097152);
  ushort* Wvb = (ushort*)(ws + 6 * SZ + 2 * 2097152);
  ushort* Wob = (ushort*)(ws + 6 * SZ + 3 * 2097152);
  ushort* Mp  = (ushort*)(ws + 6 * SZ + 4 * 2097152);  // 2 MB packed mask

  cast_bf16_k<<<8192, 256, 0, stream>>>(X, Xb, 2097152, 1.0f);
  cast_bf16_k<<<8192, 256, 0, stream>>>(Y, Yb, 2097152, 1.0f);
  cast_bf16_k<<<1024, 256, 0, stream>>>(Wq, Wqb, 262144, SC);   // Q pre-scaled
  cast_bf16_k<<<1024, 256, 0, stream>>>(Wk, Wkb, 262144, 1.0f);
  cast_bf16_k<<<1024, 256, 0, stream>>>(Wv, Wvb, 262144, 1.0f);
  cast_bf16_k<<<1024, 256, 0, stream>>>(Wo, Wob, 262144, 1.0f);
  mask_pack_k<<<4096, 256, 0, stream>>>(mask, Mp, 1048576);

  gemm_bt<0><<<512, 256, 0, stream>>>(Xb, Wqb, bq, (void*)Qb, SC);
  gemm_bt<0><<<512, 256, 0, stream>>>(Yb, Wkb, bk, (void*)Kb, 1.0f);
  gemm_bt<1><<<512, 256, 0, stream>>>(Yb, Wvb, bv, (void*)Vt, 1.0f);

  attn_k<<<8192, 1024, 0, stream>>>(Qb, Kb, Vt, Mp, out + 8388608, Cc);

  gemm_bt<2><<<512, 256, 0, stream>>>(Cc, Wob, bo, (void*)out, 1.0f);
}

// Round 11
// 795.464 us; speedup vs baseline: 1.1518x; 1.1518x over previous
//
#include <hip/hip_runtime.h>
#include <stdint.h>

typedef __attribute__((ext_vector_type(8))) short bf8_t;   // 8 bf16 (4 VGPRs) MFMA A/B frag
typedef __attribute__((ext_vector_type(4))) float f4_t;    // MFMA C/D frag

#define DEVI static __device__ __forceinline__

// fp32 -> bf16 round-to-nearest-even
DEVI unsigned short f2b(float f) {
  unsigned u = __builtin_bit_cast(unsigned, f);
  u += 0x7fffu + ((u >> 16) & 1u);
  return (unsigned short)(u >> 16);
}

DEVI float b2f(unsigned short v) {
  return __builtin_bit_cast(float, (unsigned)v << 16);
}

// ---------------------------------------------------------------- cast kernel (with optional scale fold)
__global__ void cast_bf16_k(const float* __restrict__ src, ushort* __restrict__ dst, int n4, float scale) {
  int i = blockIdx.x * 256 + threadIdx.x;
  if (i >= n4) return;
  float4 v = reinterpret_cast<const float4*>(src)[i];
  ushort4 o;
  o.x = f2b(v.x * scale); o.y = f2b(v.y * scale); o.z = f2b(v.z * scale); o.w = f2b(v.w * scale);
  reinterpret_cast<ushort4*>(dst)[i] = o;
}

// ---------------------------------------------------------------- mask bit-pack
// mask int32 (b,n,m) in {0,1}  ->  packed ushort words: word i covers cols i*16..i*16+15,
// bit j = mask[col i*16+j]. Total 4*2048*128 ushorts = 2 MB (L2-resident in attn).
__global__ void mask_pack_k(const int* __restrict__ mask, ushort* __restrict__ mp, int nwords) {
  int i = blockIdx.x * 256 + threadIdx.x;
  if (i >= nwords) return;
  const int4* src = reinterpret_cast<const int4*>(mask + (size_t)i * 16);
  unsigned v = 0;
#pragma unroll
  for (int j = 0; j < 4; j++) {
    int4 m = src[j];
    v |= ((unsigned)(m.x & 1) << (j * 4 + 0));
    v |= ((unsigned)(m.y & 1) << (j * 4 + 1));
    v |= ((unsigned)(m.z & 1) << (j * 4 + 2));
    v |= ((unsigned)(m.w & 1) << (j * 4 + 3));
  }
  mp[i] = (ushort)v;
}

// ---------------------------------------------------------------- GEMM: C[n][o] = sum_d A[n][d]*W[o][d] + bias[o]*bscale
template<int MODE>
__global__ __launch_bounds__(256, 3) void gemm_bt(const ushort* __restrict__ A,
                                                  const ushort* __restrict__ W,
                                                  const float* __restrict__ bias,
                                                  void* __restrict__ outp, float bscale) {
  // XOR-swizzled LDS tiles: row stride 64 bf16 (128B), unit (16B) u stored at u ^ (row&7)
  __shared__ ushort As[128 * 64];
  __shared__ ushort Ws[128 * 64];
  const int t = threadIdx.x;
  const int tileCol = blockIdx.x & 7;
  const int tileRow = blockIdx.x >> 3;
  const int rowBase = tileRow * 128;
  const int colBase = tileCol * 128;

  const int r32 = t >> 3;
  const int cu = t & 7;
  const int w = t >> 6;
  const int lane = t & 63;
  const int q = lane >> 4;
  const int c = lane & 15;
  const int wr = (w >> 1) * 64;
  const int wc = (w & 1) * 64;

  f4_t acc[4][4];
#pragma unroll
  for (int i = 0; i < 4; i++)
#pragma unroll
    for (int j = 0; j < 4; j++) acc[i][j] = (f4_t){0.f, 0.f, 0.f, 0.f};

  for (int k0 = 0; k0 < 1024; k0 += 64) {
#pragma unroll
    for (int rs = 0; rs < 4; rs++) {
      int r = rs * 32 + r32;
      int4 va = *reinterpret_cast<const int4*>(A + (size_t)(rowBase + r) * 1024 + k0 + cu * 8);
      int4 vw = *reinterpret_cast<const int4*>(W + (size_t)(colBase + r) * 1024 + k0 + cu * 8);
      *reinterpret_cast<int4*>(&As[r * 64 + ((cu ^ (r & 7)) << 3)]) = va;
      *reinterpret_cast<int4*>(&Ws[r * 64 + ((cu ^ (r & 7)) << 3)]) = vw;
    }
    __syncthreads();
    bf8_t af[4][2], bfr[4][2];
#pragma unroll
    for (int i = 0; i < 4; i++) {
      int ra = wr + i * 16 + c;
      int rb = wc + i * 16 + c;
#pragma unroll
      for (int s = 0; s < 2; s++) {
        af[i][s] = *reinterpret_cast<const bf8_t*>(&As[ra * 64 + (((s * 4 + q) ^ (ra & 7)) << 3)]);
        bfr[i][s] = *reinterpret_cast<const bf8_t*>(&Ws[rb * 64 + (((s * 4 + q) ^ (rb & 7)) << 3)]);
      }
    }
#pragma unroll
    for (int i = 0; i < 4; i++)
#pragma unroll
      for (int j = 0; j < 4; j++) {
        acc[i][j] = __builtin_amdgcn_mfma_f32_16x16x32_bf16(af[i][0], bfr[j][0], acc[i][j], 0, 0, 0);
        acc[i][j] = __builtin_amdgcn_mfma_f32_16x16x32_bf16(af[i][1], bfr[j][1], acc[i][j], 0, 0, 0);
      }
    __syncthreads();
  }

  // epilogue: D layout col=lane&15, row=(lane>>4)*4+reg  [measured m89/m91]
#pragma unroll
  for (int j = 0; j < 4; j++) {
    int col = colBase + wc + j * 16 + c;
    float bj = bias[col] * bscale;
#pragma unroll
    for (int i = 0; i < 4; i++) {
      int rbase = rowBase + wr + i * 16 + q * 4;
      if (MODE == 0) {
        ushort* out = (ushort*)outp;
#pragma unroll
        for (int reg = 0; reg < 4; reg++)
          out[(size_t)(rbase + reg) * 1024 + col] = f2b(acc[i][j][reg] + bj);
      } else if (MODE == 1) {
        ushort* out = (ushort*)outp;
        int bb = rbase >> 11;
        int nl = rbase & 2047;
        ushort4 v;
        v.x = f2b(acc[i][j][0] + bj);
        v.y = f2b(acc[i][j][1] + bj);
        v.z = f2b(acc[i][j][2] + bj);
        v.w = f2b(acc[i][j][3] + bj);
        *reinterpret_cast<ushort4*>(out + ((size_t)(bb * 1024 + col) * 2048 + nl)) = v;
      } else {
        float* out = (float*)outp;
#pragma unroll
        for (int reg = 0; reg < 4; reg++)
          out[(size_t)(rbase + reg) * 1024 + col] = acc[i][j][reg] + bj;
      }
    }
  }
}

// ---------------------------------------------------------------- fused attention: P in LDS (R8 structure)
// Block: one (b,h), 16 q-rows, 512 threads; 8 waves x 256-col m-strips. Q PRE-SCALED by
// (1/sqrt(64))*log2(e) -> exp2(s) is the softmax numerator.
// R8 (best) structure kept verbatim: sweep -> barrier -> {PV, beta} -> barrier -> merge.
// R11 change: MASK LOADS HOISTED OUT OF THE CHUNK LOOP. R8 issued 4 scalar mask loads AFTER
// each chunk's K loads and consumed them immediately; vmcnt is a FIFO, so waiting on the
// trailing mask load drained ALL in-flight K loads each chunk — an implicit vmcnt(0) per
// chunk (same serializer as R5's fence). Now each 8-chunk half loads its mask bits as
// 4 x int4 up front (R1's pass-1 shape: measured VGPR=36, no spill), so chunk mb waits only
// on its own K loads and later K prefetches stay in flight. Pass-1 VMEM instrs: 96 -> 40.
__global__ __launch_bounds__(512, 4) void attn_k(const ushort* __restrict__ Qb,
                                                 const ushort* __restrict__ Kb,
                                                 const ushort* __restrict__ Vt,
                                                 const ushort* __restrict__ Mp,
                                                 float* __restrict__ beta,
                                                 ushort* __restrict__ Cc) {
  __shared__ ushort Pl[8 * 16 * 256];  // 64KB: P strips [w][16 rows][256 cols], 16B-unit swizzled
  __shared__ float lpart[8][16];
  float* OwU = (float*)Pl;             // union: Ow[8][16][68] after P consumed

  // XCD-affine swizzle: head-pairs pinned to XCD so K/V stay L2-resident
  const int L = blockIdx.x;
  const int bh = (L >> 10) * 8 + (L & 7);  // 0..63
  const int qt = (L >> 3) & 127;
  const int b = bh >> 4;
  const int h = bh & 15;
  const int n0 = qt * 16;

  const int t = threadIdx.x;
  const int w = t >> 6;    // 0..7
  const int lane = t & 63;
  const int q = lane >> 4;
  const int c = lane & 15;

  const size_t qbase = ((size_t)(b * 2048 + n0 + c)) * 1024 + h * 64 + q * 8;
  bf8_t qa0 = *reinterpret_cast<const bf8_t*>(Qb + qbase);
  bf8_t qa1 = *reinterpret_cast<const bf8_t*>(Qb + qbase + 32);

  const int mBase = w * 256;
  const size_t kbase0 = ((size_t)(b * 2048 + mBase + c)) * 1024 + h * 64 + q * 8;
  const ushort* mpk = Mp + ((size_t)(b * 2048 + n0)) * 128 + (mBase >> 4);
  ushort* Ps = Pl + w * (16 * 256);  // this wave's strip

  // ---- pass 1: QK sweep, e -> LDS strip, accumulate l. Mask pre-loaded per 8-chunk half.
  float ls[4] = {0.f, 0.f, 0.f, 0.f};
#pragma unroll
  for (int g = 0; g < 2; ++g) {
    int4 mrow[4];
#pragma unroll
    for (int r = 0; r < 4; r++)
      mrow[r] = *reinterpret_cast<const int4*>(mpk + (size_t)(q * 4 + r) * 128 + g * 8);
#pragma unroll
    for (int mi = 0; mi < 8; ++mi) {
      const int mb = g * 8 + mi;
      const ushort* kp = Kb + kbase0 + (size_t)mb * 16 * 1024;
      bf8_t k0 = *reinterpret_cast<const bf8_t*>(kp);
      bf8_t k1 = *reinterpret_cast<const bf8_t*>(kp + 32);
      f4_t s = (f4_t){0.f, 0.f, 0.f, 0.f};
      s = __builtin_amdgcn_mfma_f32_16x16x32_bf16(qa0, k0, s, 0, 0, 0);
      s = __builtin_amdgcn_mfma_f32_16x16x32_bf16(qa1, k1, s, 0, 0, 0);
      const int u = mb * 2 + (c >> 3);
#pragma unroll
      for (int reg = 0; reg < 4; reg++) {
        const int row = q * 4 + reg;
        unsigned mword = (unsigned)((mi >> 1) == 0 ? mrow[reg].x
                                  : (mi >> 1) == 1 ? mrow[reg].y
                                  : (mi >> 1) == 2 ? mrow[reg].z
                                                   : mrow[reg].w);
        unsigned masked = (mword >> ((mi & 1) * 16 + c)) & 1u;
        float e = masked ? 0.f : __builtin_amdgcn_exp2f(s[reg]);
        ls[reg] += e;
        Ps[row * 256 + (((u ^ (row & 7)) << 3) | (c & 7))] = f2b(e);
      }
    }
  }

  // ---- l reduce -> lpart
#pragma unroll
  for (int reg = 0; reg < 4; reg++) {
    ls[reg] += __shfl_xor(ls[reg], 1);
    ls[reg] += __shfl_xor(ls[reg], 2);
    ls[reg] += __shfl_xor(ls[reg], 4);
    ls[reg] += __shfl_xor(ls[reg], 8);
  }
  if (c == 0) {
#pragma unroll
    for (int reg = 0; reg < 4; reg++) lpart[w][q * 4 + reg] = ls[reg];
  }
  __syncthreads();  // P strips + lpart visible to all

  // ---- pass 2a: PV from own LDS strip (unnormalized); V loads free to pipeline
  f4_t o[4];
#pragma unroll
  for (int db = 0; db < 4; db++) o[db] = (f4_t){0.f, 0.f, 0.f, 0.f};
  const size_t vbase = ((size_t)(b * 1024 + h * 64 + c)) * 2048 + mBase + q * 8;
#pragma unroll 2
  for (int p = 0; p < 8; ++p) {
    const int u = p * 4 + q;
    bf8_t pa = *reinterpret_cast<const bf8_t*>(&Ps[c * 256 + ((u ^ (c & 7)) << 3)]);
    const int m0 = p * 32;
#pragma unroll
    for (int db = 0; db < 4; db++) {
      bf8_t vf = *reinterpret_cast<const bf8_t*>(Vt + vbase + (size_t)db * 16 * 2048 + m0);
      o[db] = __builtin_amdgcn_mfma_f32_16x16x32_bf16(pa, vf, o[db], 0, 0, 0);
    }
  }

  // ---- pass 2b: beta = P * (1/l), vectorized: thread t -> row r=t>>5, unit j=t&31
  {
    const int r = t >> 5;
    const int j = t & 31;
    float lsum = 0.f;
#pragma unroll
    for (int ww = 0; ww < 8; ww++) lsum += lpart[ww][r];
    const float li = 1.0f / lsum;
    float* brow = beta + ((size_t)(bh * 2048 + n0 + r)) * 2048;
#pragma unroll
    for (int i = 0; i < 8; ++i) {  // strip i holds cols i*256..i*256+255
      bf8_t pv = *reinterpret_cast<const bf8_t*>(&Pl[(i * 16 + r) * 256 + ((j ^ (r & 7)) << 3)]);
      float4 f0, f1;
      f0.x = b2f((unsigned short)pv[0]) * li;
      f0.y = b2f((unsigned short)pv[1]) * li;
      f0.z = b2f((unsigned short)pv[2]) * li;
      f0.w = b2f((unsigned short)pv[3]) * li;
      f1.x = b2f((unsigned short)pv[4]) * li;
      f1.y = b2f((unsigned short)pv[5]) * li;
      f1.z = b2f((unsigned short)pv[6]) * li;
      f1.w = b2f((unsigned short)pv[7]) * li;
      float* dst = brow + i * 256 + j * 8;
      *reinterpret_cast<float4*>(dst) = f0;
      *reinterpret_cast<float4*>(dst + 4) = f1;
    }
  }

  __syncthreads();  // all P reads done -> safe to overwrite with Ow

  // ---- merge O across 8 waves via union region, scale by 1/l, store concat bf16
#pragma unroll
  for (int db = 0; db < 4; db++)
#pragma unroll
    for (int reg = 0; reg < 4; reg++)
      OwU[(w * 16 + q * 4 + reg) * 68 + db * 16 + c] = o[db][reg];
  __syncthreads();
  if (t < 256) {
    int r = t >> 4;
    int d0 = (t & 15) * 4;
    float lsum = 0.f;
#pragma unroll
    for (int ww = 0; ww < 8; ww++) lsum += lpart[ww][r];
    float sl = 1.0f / lsum;
    float4 acc = (float4){0.f, 0.f, 0.f, 0.f};
#pragma unroll
    for (int ww = 0; ww < 8; ww++) {
      float4 sv = *reinterpret_cast<const float4*>(&OwU[(ww * 16 + r) * 68 + d0]);
      acc.x += sv.x; acc.y += sv.y; acc.z += sv.z; acc.w += sv.w;
    }
    ushort4 ov;
    ov.x = f2b(acc.x * sl);
    ov.y = f2b(acc.y * sl);
    ov.z = f2b(acc.z * sl);
    ov.w = f2b(acc.w * sl);
    *reinterpret_cast<ushort4*>(Cc + ((size_t)(b * 2048 + n0 + r)) * 1024 + h * 64 + d0) = ov;
  }
}

// ---------------------------------------------------------------- launch
extern "C" void kernel_launch(void* const* d_in, const int* in_sizes, int n_in,
                              void* d_out, int out_size, void* d_ws, size_t ws_size,
                              hipStream_t stream) {
  (void)in_sizes; (void)n_in; (void)out_size; (void)ws_size;
  const float* X = (const float*)d_in[0];
  const float* Y = (const float*)d_in[1];
  const int* mask = (const int*)d_in[2];
  const float* Wq = (const float*)d_in[3];
  const float* bq = (const float*)d_in[4];
  const float* Wk = (const float*)d_in[5];
  const float* bk = (const float*)d_in[6];
  const float* Wv = (const float*)d_in[7];
  const float* bv = (const float*)d_in[8];
  const float* Wo = (const float*)d_in[9];
  const float* bo = (const float*)d_in[10];
  float* out = (float*)d_out;

  const float SC = 0.18033688011112042f;  // (1/sqrt(64)) * log2(e), folded into Wq/bq

  char* ws = (char*)d_ws;
  const size_t SZ = 16777216;  // 8192*1024*2B
  ushort* Xb = (ushort*)(ws);
  ushort* Yb = (ushort*)(ws + SZ);
  ushort* Qb = (ushort*)(ws + 2 * SZ);
  ushort* Kb = (ushort*)(ws + 3 * SZ);
  ushort* Vt = (ushort*)(ws + 4 * SZ);
  ushort* Cc = (ushort*)(ws + 5 * SZ);
  ushort* Wqb = (ushort*)(ws + 6 * SZ);
  ushort* Wkb = (ushort*)(ws + 6 * SZ + 2097152);
  ushort* Wvb = (ushort*)(ws + 6 * SZ + 2 * 2097152);
  ushort* Wob = (ushort*)(ws + 6 * SZ + 3 * 2097152);
  ushort* Mp  = (ushort*)(ws + 6 * SZ + 4 * 2097152);  // 2 MB packed mask

  cast_bf16_k<<<8192, 256, 0, stream>>>(X, Xb, 2097152, 1.0f);
  cast_bf16_k<<<8192, 256, 0, stream>>>(Y, Yb, 2097152, 1.0f);
  cast_bf16_k<<<1024, 256, 0, stream>>>(Wq, Wqb, 262144, SC);   // Q pre-scaled
  cast_bf16_k<<<1024, 256, 0, stream>>>(Wk, Wkb, 262144, 1.0f);
  cast_bf16_k<<<1024, 256, 0, stream>>>(Wv, Wvb, 262144, 1.0f);
  cast_bf16_k<<<1024, 256, 0, stream>>>(Wo, Wob, 262144, 1.0f);
  mask_pack_k<<<4096, 256, 0, stream>>>(mask, Mp, 1048576);

  gemm_bt<0><<<512, 256, 0, stream>>>(Xb, Wqb, bq, (void*)Qb, SC);
  gemm_bt<0><<<512, 256, 0, stream>>>(Yb, Wkb, bk, (void*)Kb, 1.0f);
  gemm_bt<1><<<512, 256, 0, stream>>>(Yb, Wvb, bv, (void*)Vt, 1.0f);

  attn_k<<<8192, 512, 0, stream>>>(Qb, Kb, Vt, Mp, out + 8388608, Cc);

  gemm_bt<2><<<512, 256, 0, stream>>>(Cc, Wob, bo, (void*)out, 1.0f);
}

// Round 12
// 794.992 us; speedup vs baseline: 1.1525x; 1.0006x over previous
//
#include <hip/hip_runtime.h>
#include <stdint.h>

typedef __attribute__((ext_vector_type(8))) short bf8_t;   // 8 bf16 (4 VGPRs) MFMA A/B frag
typedef __attribute__((ext_vector_type(4))) float f4_t;    // MFMA C/D frag

#define DEVI static __device__ __forceinline__

// fp32 -> bf16 round-to-nearest-even
DEVI unsigned short f2b(float f) {
  unsigned u = __builtin_bit_cast(unsigned, f);
  u += 0x7fffu + ((u >> 16) & 1u);
  return (unsigned short)(u >> 16);
}

DEVI float b2f(unsigned short v) {
  return __builtin_bit_cast(float, (unsigned)v << 16);
}

// ---------------------------------------------------------------- cast kernel (with optional scale fold)
__global__ void cast_bf16_k(const float* __restrict__ src, ushort* __restrict__ dst, int n4, float scale) {
  int i = blockIdx.x * 256 + threadIdx.x;
  if (i >= n4) return;
  float4 v = reinterpret_cast<const float4*>(src)[i];
  ushort4 o;
  o.x = f2b(v.x * scale); o.y = f2b(v.y * scale); o.z = f2b(v.z * scale); o.w = f2b(v.w * scale);
  reinterpret_cast<ushort4*>(dst)[i] = o;
}

// ---------------------------------------------------------------- mask bit-pack
// mask int32 (b,n,m) in {0,1}  ->  packed ushort words: word i covers cols i*16..i*16+15,
// bit j = mask[col i*16+j]. Total 4*2048*128 ushorts = 2 MB (L2-resident in attn).
__global__ void mask_pack_k(const int* __restrict__ mask, ushort* __restrict__ mp, int nwords) {
  int i = blockIdx.x * 256 + threadIdx.x;
  if (i >= nwords) return;
  const int4* src = reinterpret_cast<const int4*>(mask + (size_t)i * 16);
  unsigned v = 0;
#pragma unroll
  for (int j = 0; j < 4; j++) {
    int4 m = src[j];
    v |= ((unsigned)(m.x & 1) << (j * 4 + 0));
    v |= ((unsigned)(m.y & 1) << (j * 4 + 1));
    v |= ((unsigned)(m.z & 1) << (j * 4 + 2));
    v |= ((unsigned)(m.w & 1) << (j * 4 + 3));
  }
  mp[i] = (ushort)v;
}

// ---------------------------------------------------------------- GEMM: C[n][o] = sum_d A[n][d]*W[o][d] + bias[o]*bscale
template<int MODE>
__global__ __launch_bounds__(256, 3) void gemm_bt(const ushort* __restrict__ A,
                                                  const ushort* __restrict__ W,
                                                  const float* __restrict__ bias,
                                                  void* __restrict__ outp, float bscale) {
  // XOR-swizzled LDS tiles: row stride 64 bf16 (128B), unit (16B) u stored at u ^ (row&7)
  __shared__ ushort As[128 * 64];
  __shared__ ushort Ws[128 * 64];
  const int t = threadIdx.x;
  const int tileCol = blockIdx.x & 7;
  const int tileRow = blockIdx.x >> 3;
  const int rowBase = tileRow * 128;
  const int colBase = tileCol * 128;

  const int r32 = t >> 3;
  const int cu = t & 7;
  const int w = t >> 6;
  const int lane = t & 63;
  const int q = lane >> 4;
  const int c = lane & 15;
  const int wr = (w >> 1) * 64;
  const int wc = (w & 1) * 64;

  f4_t acc[4][4];
#pragma unroll
  for (int i = 0; i < 4; i++)
#pragma unroll
    for (int j = 0; j < 4; j++) acc[i][j] = (f4_t){0.f, 0.f, 0.f, 0.f};

  for (int k0 = 0; k0 < 1024; k0 += 64) {
#pragma unroll
    for (int rs = 0; rs < 4; rs++) {
      int r = rs * 32 + r32;
      int4 va = *reinterpret_cast<const int4*>(A + (size_t)(rowBase + r) * 1024 + k0 + cu * 8);
      int4 vw = *reinterpret_cast<const int4*>(W + (size_t)(colBase + r) * 1024 + k0 + cu * 8);
      *reinterpret_cast<int4*>(&As[r * 64 + ((cu ^ (r & 7)) << 3)]) = va;
      *reinterpret_cast<int4*>(&Ws[r * 64 + ((cu ^ (r & 7)) << 3)]) = vw;
    }
    __syncthreads();
    bf8_t af[4][2], bfr[4][2];
#pragma unroll
    for (int i = 0; i < 4; i++) {
      int ra = wr + i * 16 + c;
      int rb = wc + i * 16 + c;
#pragma unroll
      for (int s = 0; s < 2; s++) {
        af[i][s] = *reinterpret_cast<const bf8_t*>(&As[ra * 64 + (((s * 4 + q) ^ (ra & 7)) << 3)]);
        bfr[i][s] = *reinterpret_cast<const bf8_t*>(&Ws[rb * 64 + (((s * 4 + q) ^ (rb & 7)) << 3)]);
      }
    }
#pragma unroll
    for (int i = 0; i < 4; i++)
#pragma unroll
      for (int j = 0; j < 4; j++) {
        acc[i][j] = __builtin_amdgcn_mfma_f32_16x16x32_bf16(af[i][0], bfr[j][0], acc[i][j], 0, 0, 0);
        acc[i][j] = __builtin_amdgcn_mfma_f32_16x16x32_bf16(af[i][1], bfr[j][1], acc[i][j], 0, 0, 0);
      }
    __syncthreads();
  }

  // epilogue: D layout col=lane&15, row=(lane>>4)*4+reg  [measured m89/m91]
#pragma unroll
  for (int j = 0; j < 4; j++) {
    int col = colBase + wc + j * 16 + c;
    float bj = bias[col] * bscale;
#pragma unroll
    for (int i = 0; i < 4; i++) {
      int rbase = rowBase + wr + i * 16 + q * 4;
      if (MODE == 0) {
        ushort* out = (ushort*)outp;
#pragma unroll
        for (int reg = 0; reg < 4; reg++)
          out[(size_t)(rbase + reg) * 1024 + col] = f2b(acc[i][j][reg] + bj);
      } else if (MODE == 1) {
        ushort* out = (ushort*)outp;
        int bb = rbase >> 11;
        int nl = rbase & 2047;
        ushort4 v;
        v.x = f2b(acc[i][j][0] + bj);
        v.y = f2b(acc[i][j][1] + bj);
        v.z = f2b(acc[i][j][2] + bj);
        v.w = f2b(acc[i][j][3] + bj);
        *reinterpret_cast<ushort4*>(out + ((size_t)(bb * 1024 + col) * 2048 + nl)) = v;
      } else {
        float* out = (float*)outp;
#pragma unroll
        for (int reg = 0; reg < 4; reg++)
          out[(size_t)(rbase + reg) * 1024 + col] = acc[i][j][reg] + bj;
      }
    }
  }
}

// ---------------------------------------------------------------- fused attention: P in LDS (R8 structure, pass-2 overhaul)
// Block: one (b,h), 16 q-rows, 512 threads; 8 waves x 256-col m-strips. Q PRE-SCALED by
// (1/sqrt(64))*log2(e) -> exp2(s) is the softmax numerator.
// R8/R11 base (best, 795 total): sweep -> barrier -> {PV, beta} -> barrier -> merge.
// R12 pass-2 overhaul (phases were bursty: write-burst beta after compute-only PV; R10 proved
// cross-block TLP can't overlap them since blocks are phase-synchronized):
//   (a) PV and beta INTERLEAVED in one 8-iter loop: beta's cvt+store fills PV's MFMA/V-load
//       shadows; the write stream spreads across the whole phase instead of a tail burst.
//   (b) DENSE beta stores: wave's 64 lanes write 2 rows x 512B contiguous (16 full 64B
//       lines/instr) vs old half-density 16B-per-32B partial lines.
//   (c) s_setprio(1) around the PV MFMA cluster (guide T5: +4-7% attn).
__global__ __launch_bounds__(512, 4) void attn_k(const ushort* __restrict__ Qb,
                                                 const ushort* __restrict__ Kb,
                                                 const ushort* __restrict__ Vt,
                                                 const ushort* __restrict__ Mp,
                                                 float* __restrict__ beta,
                                                 ushort* __restrict__ Cc) {
  __shared__ ushort Pl[8 * 16 * 256];  // 64KB: P strips [w][16 rows][256 cols], 16B-unit swizzled
  __shared__ float lpart[8][16];
  float* OwU = (float*)Pl;             // union: Ow[8][16][68] after P consumed

  // XCD-affine swizzle: head-pairs pinned to XCD so K/V stay L2-resident
  const int L = blockIdx.x;
  const int bh = (L >> 10) * 8 + (L & 7);  // 0..63
  const int qt = (L >> 3) & 127;
  const int b = bh >> 4;
  const int h = bh & 15;
  const int n0 = qt * 16;

  const int t = threadIdx.x;
  const int w = t >> 6;    // 0..7
  const int lane = t & 63;
  const int q = lane >> 4;
  const int c = lane & 15;

  const size_t qbase = ((size_t)(b * 2048 + n0 + c)) * 1024 + h * 64 + q * 8;
  bf8_t qa0 = *reinterpret_cast<const bf8_t*>(Qb + qbase);
  bf8_t qa1 = *reinterpret_cast<const bf8_t*>(Qb + qbase + 32);

  const int mBase = w * 256;
  const size_t kbase0 = ((size_t)(b * 2048 + mBase + c)) * 1024 + h * 64 + q * 8;
  const ushort* mpk = Mp + ((size_t)(b * 2048 + n0)) * 128 + (mBase >> 4);
  ushort* Ps = Pl + w * (16 * 256);  // this wave's strip

  // ---- pass 1: QK sweep, e -> LDS strip, accumulate l. Mask pre-loaded per 8-chunk half.
  float ls[4] = {0.f, 0.f, 0.f, 0.f};
#pragma unroll
  for (int g = 0; g < 2; ++g) {
    int4 mrow[4];
#pragma unroll
    for (int r = 0; r < 4; r++)
      mrow[r] = *reinterpret_cast<const int4*>(mpk + (size_t)(q * 4 + r) * 128 + g * 8);
#pragma unroll
    for (int mi = 0; mi < 8; ++mi) {
      const int mb = g * 8 + mi;
      const ushort* kp = Kb + kbase0 + (size_t)mb * 16 * 1024;
      bf8_t k0 = *reinterpret_cast<const bf8_t*>(kp);
      bf8_t k1 = *reinterpret_cast<const bf8_t*>(kp + 32);
      f4_t s = (f4_t){0.f, 0.f, 0.f, 0.f};
      s = __builtin_amdgcn_mfma_f32_16x16x32_bf16(qa0, k0, s, 0, 0, 0);
      s = __builtin_amdgcn_mfma_f32_16x16x32_bf16(qa1, k1, s, 0, 0, 0);
      const int u = mb * 2 + (c >> 3);
#pragma unroll
      for (int reg = 0; reg < 4; reg++) {
        const int row = q * 4 + reg;
        unsigned mword = (unsigned)((mi >> 1) == 0 ? mrow[reg].x
                                  : (mi >> 1) == 1 ? mrow[reg].y
                                  : (mi >> 1) == 2 ? mrow[reg].z
                                                   : mrow[reg].w);
        unsigned masked = (mword >> ((mi & 1) * 16 + c)) & 1u;
        float e = masked ? 0.f : __builtin_amdgcn_exp2f(s[reg]);
        ls[reg] += e;
        Ps[row * 256 + (((u ^ (row & 7)) << 3) | (c & 7))] = f2b(e);
      }
    }
  }

  // ---- l reduce -> lpart
#pragma unroll
  for (int reg = 0; reg < 4; reg++) {
    ls[reg] += __shfl_xor(ls[reg], 1);
    ls[reg] += __shfl_xor(ls[reg], 2);
    ls[reg] += __shfl_xor(ls[reg], 4);
    ls[reg] += __shfl_xor(ls[reg], 8);
  }
  if (c == 0) {
#pragma unroll
    for (int reg = 0; reg < 4; reg++) lpart[w][q * 4 + reg] = ls[reg];
  }
  __syncthreads();  // P strips + lpart visible to all

  // ---- pass 2: PV (own strip) interleaved with DENSE beta writes (all strips)
  f4_t o[4];
#pragma unroll
  for (int db = 0; db < 4; db++) o[db] = (f4_t){0.f, 0.f, 0.f, 0.f};
  const size_t vbase = ((size_t)(b * 1024 + h * 64 + c)) * 2048 + mBase + q * 8;

  // dense-beta mapping: wave w -> rows 2w, 2w+1; lane>>5 selects row, j2=lane&31 covers
  // 128 floats per iter (64 lanes -> 2 rows x 512B contiguous per store instr)
  const int br = 2 * w + (lane >> 5);
  const int j2 = lane & 31;
  float lsum_b = 0.f;
#pragma unroll
  for (int ww = 0; ww < 8; ww++) lsum_b += lpart[ww][br];
  const float li = 1.0f / lsum_b;
  float* brow = beta + ((size_t)(bh * 2048 + n0 + br)) * 2048;

#pragma unroll
  for (int p = 0; p < 8; ++p) {
    // PV part (own strip)
    const int u = p * 4 + q;
    bf8_t pa = *reinterpret_cast<const bf8_t*>(&Ps[c * 256 + ((u ^ (c & 7)) << 3)]);
    const int m0 = p * 32;
    __builtin_amdgcn_s_setprio(1);
#pragma unroll
    for (int db = 0; db < 4; db++) {
      bf8_t vf = *reinterpret_cast<const bf8_t*>(Vt + vbase + (size_t)db * 16 * 2048 + m0);
      o[db] = __builtin_amdgcn_mfma_f32_16x16x32_bf16(pa, vf, o[db], 0, 0, 0);
    }
    __builtin_amdgcn_s_setprio(0);
    // beta part: 2 dense units (k = 2p, 2p+1), each 128 floats of row br
#pragma unroll
    for (int kk = 0; kk < 2; ++kk) {
      const int k = p * 2 + kk;
      const int s = k >> 1;                       // source strip
      const int off = (k & 1) * 128 + j2 * 4;     // col within strip
      const int uu = off >> 3;
      const int e4 = off & 7;                     // 0 or 4
      ushort4 pv4 = *reinterpret_cast<const ushort4*>(
          &Pl[s * 4096 + br * 256 + ((uu ^ (br & 7)) << 3) + e4]);
      float4 f;
      f.x = b2f(pv4.x) * li;
      f.y = b2f(pv4.y) * li;
      f.z = b2f(pv4.z) * li;
      f.w = b2f(pv4.w) * li;
      *reinterpret_cast<float4*>(brow + k * 128 + j2 * 4) = f;
    }
  }

  __syncthreads();  // all P reads done -> safe to overwrite with Ow

  // ---- merge O across 8 waves via union region, scale by 1/l, store concat bf16
#pragma unroll
  for (int db = 0; db < 4; db++)
#pragma unroll
    for (int reg = 0; reg < 4; reg++)
      OwU[(w * 16 + q * 4 + reg) * 68 + db * 16 + c] = o[db][reg];
  __syncthreads();
  if (t < 256) {
    int r = t >> 4;
    int d0 = (t & 15) * 4;
    float lsum = 0.f;
#pragma unroll
    for (int ww = 0; ww < 8; ww++) lsum += lpart[ww][r];
    float sl = 1.0f / lsum;
    float4 acc = (float4){0.f, 0.f, 0.f, 0.f};
#pragma unroll
    for (int ww = 0; ww < 8; ww++) {
      float4 sv = *reinterpret_cast<const float4*>(&OwU[(ww * 16 + r) * 68 + d0]);
      acc.x += sv.x; acc.y += sv.y; acc.z += sv.z; acc.w += sv.w;
    }
    ushort4 ov;
    ov.x = f2b(acc.x * sl);
    ov.y = f2b(acc.y * sl);
    ov.z = f2b(acc.z * sl);
    ov.w = f2b(acc.w * sl);
    *reinterpret_cast<ushort4*>(Cc + ((size_t)(b * 2048 + n0 + r)) * 1024 + h * 64 + d0) = ov;
  }
}

// ---------------------------------------------------------------- launch
extern "C" void kernel_launch(void* const* d_in, const int* in_sizes, int n_in,
                              void* d_out, int out_size, void* d_ws, size_t ws_size,
                              hipStream_t stream) {
  (void)in_sizes; (void)n_in; (void)out_size; (void)ws_size;
  const float* X = (const float*)d_in[0];
  const float* Y = (const float*)d_in[1];
  const int* mask = (const int*)d_in[2];
  const float* Wq = (const float*)d_in[3];
  const float* bq = (const float*)d_in[4];
  const float* Wk = (const float*)d_in[5];
  const float* bk = (const float*)d_in[6];
  const float* Wv = (const float*)d_in[7];
  const float* bv = (const float*)d_in[8];
  const float* Wo = (const float*)d_in[9];
  const float* bo = (const float*)d_in[10];
  float* out = (float*)d_out;

  const float SC = 0.18033688011112042f;  // (1/sqrt(64)) * log2(e), folded into Wq/bq

  char* ws = (char*)d_ws;
  const size_t SZ = 16777216;  // 8192*1024*2B
  ushort* Xb = (ushort*)(ws);
  ushort* Yb = (ushort*)(ws + SZ);
  ushort* Qb = (ushort*)(ws + 2 * SZ);
  ushort* Kb = (ushort*)(ws + 3 * SZ);
  ushort* Vt = (ushort*)(ws + 4 * SZ);
  ushort* Cc = (ushort*)(ws + 5 * SZ);
  ushort* Wqb = (ushort*)(ws + 6 * SZ);
  ushort* Wkb = (ushort*)(ws + 6 * SZ + 2097152);
  ushort* Wvb = (ushort*)(ws + 6 * SZ + 2 * 2097152);
  ushort* Wob = (ushort*)(ws + 6 * SZ + 3 * 2097152);
  ushort* Mp  = (ushort*)(ws + 6 * SZ + 4 * 2097152);  // 2 MB packed mask

  cast_bf16_k<<<8192, 256, 0, stream>>>(X, Xb, 2097152, 1.0f);
  cast_bf16_k<<<8192, 256, 0, stream>>>(Y, Yb, 2097152, 1.0f);
  cast_bf16_k<<<1024, 256, 0, stream>>>(Wq, Wqb, 262144, SC);   // Q pre-scaled
  cast_bf16_k<<<1024, 256, 0, stream>>>(Wk, Wkb, 262144, 1.0f);
  cast_bf16_k<<<1024, 256, 0, stream>>>(Wv, Wvb, 262144, 1.0f);
  cast_bf16_k<<<1024, 256, 0, stream>>>(Wo, Wob, 262144, 1.0f);
  mask_pack_k<<<4096, 256, 0, stream>>>(mask, Mp, 1048576);

  gemm_bt<0><<<512, 256, 0, stream>>>(Xb, Wqb, bq, (void*)Qb, SC);
  gemm_bt<0><<<512, 256, 0, stream>>>(Yb, Wkb, bk, (void*)Kb, 1.0f);
  gemm_bt<1><<<512, 256, 0, stream>>>(Yb, Wvb, bv, (void*)Vt, 1.0f);

  attn_k<<<8192, 512, 0, stream>>>(Qb, Kb, Vt, Mp, out + 8388608, Cc);

  gemm_bt<2><<<512, 256, 0, stream>>>(Cc, Wob, bo, (void*)out, 1.0f);
}

// Round 13
// 611.532 us; speedup vs baseline: 1.4982x; 1.3000x over previous
//
#include <hip/hip_runtime.h>
#include <stdint.h>

typedef __attribute__((ext_vector_type(8))) short bf8_t;   // 8 bf16 (4 VGPRs) MFMA A/B frag
typedef __attribute__((ext_vector_type(4))) float f4_t;    // MFMA C/D frag

#define DEVI static __device__ __forceinline__

// fp32 -> bf16 round-to-nearest-even
DEVI unsigned short f2b(float f) {
  unsigned u = __builtin_bit_cast(unsigned, f);
  u += 0x7fffu + ((u >> 16) & 1u);
  return (unsigned short)(u >> 16);
}

DEVI float b2f(unsigned short v) {
  return __builtin_bit_cast(float, (unsigned)v << 16);
}

// ---------------------------------------------------------------- cast kernel (with optional scale fold)
__global__ void cast_bf16_k(const float* __restrict__ src, ushort* __restrict__ dst, int n4, float scale) {
  int i = blockIdx.x * 256 + threadIdx.x;
  if (i >= n4) return;
  float4 v = reinterpret_cast<const float4*>(src)[i];
  ushort4 o;
  o.x = f2b(v.x * scale); o.y = f2b(v.y * scale); o.z = f2b(v.z * scale); o.w = f2b(v.w * scale);
  reinterpret_cast<ushort4*>(dst)[i] = o;
}

// ---------------------------------------------------------------- mask bit-pack
__global__ void mask_pack_k(const int* __restrict__ mask, ushort* __restrict__ mp, int nwords) {
  int i = blockIdx.x * 256 + threadIdx.x;
  if (i >= nwords) return;
  const int4* src = reinterpret_cast<const int4*>(mask + (size_t)i * 16);
  unsigned v = 0;
#pragma unroll
  for (int j = 0; j < 4; j++) {
    int4 m = src[j];
    v |= ((unsigned)(m.x & 1) << (j * 4 + 0));
    v |= ((unsigned)(m.y & 1) << (j * 4 + 1));
    v |= ((unsigned)(m.z & 1) << (j * 4 + 2));
    v |= ((unsigned)(m.w & 1) << (j * 4 + 3));
  }
  mp[i] = (ushort)v;
}

// ---------------------------------------------------------------- GEMM: C[n][o] = sum_d A[n][d]*W[o][d] + bias[o]*bscale
// MODE 0: out bf16 row-major (8192x1024)
// MODE 2: out fp32 row-major
// MODE 3: K chunk-tiles: Kt[((b*128+mb)*16+h)*1024 + s*512 + r*32 + c32]
//         (b=n>>11, mb=(n>>4)&127, r=n&15, h=o>>6, s=(o>>5)&1, c32=o&31) -> attn k0/k1 DENSE 1KB
// MODE 4: V pv-tiles:  Vt[((b*16+h)*64+mc)*2048 + d*32 + m32]
//         (b=n>>11, mc=(n>>5)&63, m32=n&31, h=o>>6, d=o&63) -> attn V loads DENSE 1KB x4
template<int MODE>
__global__ __launch_bounds__(256, 3) void gemm_bt(const ushort* __restrict__ A,
                                                  const ushort* __restrict__ W,
                                                  const float* __restrict__ bias,
                                                  void* __restrict__ outp, float bscale) {
  __shared__ ushort As[128 * 64];
  __shared__ ushort Ws[128 * 64];
  const int t = threadIdx.x;
  const int tileCol = blockIdx.x & 7;
  const int tileRow = blockIdx.x >> 3;
  const int rowBase = tileRow * 128;
  const int colBase = tileCol * 128;

  const int r32 = t >> 3;
  const int cu = t & 7;
  const int w = t >> 6;
  const int lane = t & 63;
  const int q = lane >> 4;
  const int c = lane & 15;
  const int wr = (w >> 1) * 64;
  const int wc = (w & 1) * 64;

  f4_t acc[4][4];
#pragma unroll
  for (int i = 0; i < 4; i++)
#pragma unroll
    for (int j = 0; j < 4; j++) acc[i][j] = (f4_t){0.f, 0.f, 0.f, 0.f};

  for (int k0 = 0; k0 < 1024; k0 += 64) {
#pragma unroll
    for (int rs = 0; rs < 4; rs++) {
      int r = rs * 32 + r32;
      int4 va = *reinterpret_cast<const int4*>(A + (size_t)(rowBase + r) * 1024 + k0 + cu * 8);
      int4 vw = *reinterpret_cast<const int4*>(W + (size_t)(colBase + r) * 1024 + k0 + cu * 8);
      *reinterpret_cast<int4*>(&As[r * 64 + ((cu ^ (r & 7)) << 3)]) = va;
      *reinterpret_cast<int4*>(&Ws[r * 64 + ((cu ^ (r & 7)) << 3)]) = vw;
    }
    __syncthreads();
    bf8_t af[4][2], bfr[4][2];
#pragma unroll
    for (int i = 0; i < 4; i++) {
      int ra = wr + i * 16 + c;
      int rb = wc + i * 16 + c;
#pragma unroll
      for (int s = 0; s < 2; s++) {
        af[i][s] = *reinterpret_cast<const bf8_t*>(&As[ra * 64 + (((s * 4 + q) ^ (ra & 7)) << 3)]);
        bfr[i][s] = *reinterpret_cast<const bf8_t*>(&Ws[rb * 64 + (((s * 4 + q) ^ (rb & 7)) << 3)]);
      }
    }
#pragma unroll
    for (int i = 0; i < 4; i++)
#pragma unroll
      for (int j = 0; j < 4; j++) {
        acc[i][j] = __builtin_amdgcn_mfma_f32_16x16x32_bf16(af[i][0], bfr[j][0], acc[i][j], 0, 0, 0);
        acc[i][j] = __builtin_amdgcn_mfma_f32_16x16x32_bf16(af[i][1], bfr[j][1], acc[i][j], 0, 0, 0);
      }
    __syncthreads();
  }

  // epilogue: D layout col=lane&15, row=(lane>>4)*4+reg  [measured m89/m91]
#pragma unroll
  for (int j = 0; j < 4; j++) {
    int col = colBase + wc + j * 16 + c;
    float bj = bias[col] * bscale;
#pragma unroll
    for (int i = 0; i < 4; i++) {
      int rbase = rowBase + wr + i * 16 + q * 4;
      if (MODE == 0) {
        ushort* out = (ushort*)outp;
#pragma unroll
        for (int reg = 0; reg < 4; reg++)
          out[(size_t)(rbase + reg) * 1024 + col] = f2b(acc[i][j][reg] + bj);
      } else if (MODE == 2) {
        float* out = (float*)outp;
#pragma unroll
        for (int reg = 0; reg < 4; reg++)
          out[(size_t)(rbase + reg) * 1024 + col] = acc[i][j][reg] + bj;
      } else if (MODE == 3) {
        // K chunk-tile scatter
        ushort* out = (ushort*)outp;
        const int bb = rbase >> 11;
        const int mb = (rbase >> 4) & 127;
        const int h = col >> 6;
        const int s = (col >> 5) & 1;
        const int c32 = col & 31;
        ushort* tb = out + (((size_t)(bb * 128 + mb) * 16 + h) << 10) + s * 512 + c32;
#pragma unroll
        for (int reg = 0; reg < 4; reg++)
          tb[(size_t)((q * 4 + reg) * 32)] = f2b(acc[i][j][reg] + bj);
      } else {
        // MODE 4: V pv-tile scatter (ushort4 along m within a tile row)
        ushort* out = (ushort*)outp;
        const int bb = rbase >> 11;
        const int mc = (rbase >> 5) & 63;
        const int m32 = rbase & 31;
        const int h = col >> 6;
        const int d = col & 63;
        ushort4 v;
        v.x = f2b(acc[i][j][0] + bj);
        v.y = f2b(acc[i][j][1] + bj);
        v.z = f2b(acc[i][j][2] + bj);
        v.w = f2b(acc[i][j][3] + bj);
        *reinterpret_cast<ushort4*>(out + ((((size_t)(bb * 16 + h) * 64 + mc) << 11) + d * 32 + m32)) = v;
      }
    }
  }
}

// ---------------------------------------------------------------- fused attention: P in LDS, DENSE K/V loads
// Block: one (b,h), 16 q-rows, 512 threads; 8 waves x 256-col m-strips. Q PRE-SCALED by
// (1/sqrt(64))*log2(e) -> exp2(s) is the softmax numerator.
// R13 change: K and V come in chunk-tiled layouts (gemm MODE 3/4) so every hot load is a
// DENSE 1KB wave-load instead of a 16-segment 64B gather (16 rows x 2KB stride). R10-R12
// showed wave count / load order / store schedule are all neutral -> the invariant resource
// was the per-CU address-path segment throughput + gather latency on the MFMA-critical path.
// Per-lane data is bit-identical to the row-major version, so fragments are unchanged.
__global__ __launch_bounds__(512, 4) void attn_k(const ushort* __restrict__ Qb,
                                                 const ushort* __restrict__ Kt,
                                                 const ushort* __restrict__ Vt,
                                                 const ushort* __restrict__ Mp,
                                                 float* __restrict__ beta,
                                                 ushort* __restrict__ Cc) {
  __shared__ ushort Pl[8 * 16 * 256];  // 64KB: P strips [w][16 rows][256 cols], 16B-unit swizzled
  __shared__ float lpart[8][16];
  float* OwU = (float*)Pl;             // union: Ow[8][16][68] after P consumed

  // XCD-affine swizzle: head-pairs pinned to XCD so K/V stay L2-resident
  const int L = blockIdx.x;
  const int bh = (L >> 10) * 8 + (L & 7);  // 0..63
  const int qt = (L >> 3) & 127;
  const int b = bh >> 4;
  const int h = bh & 15;
  const int n0 = qt * 16;

  const int t = threadIdx.x;
  const int w = t >> 6;    // 0..7
  const int lane = t & 63;
  const int q = lane >> 4;
  const int c = lane & 15;
  const int dlo = (c * 4 + q) * 8;  // dense lane offset (elements): 64 lanes -> 1KB

  const size_t qbase = ((size_t)(b * 2048 + n0 + c)) * 1024 + h * 64 + q * 8;
  bf8_t qa0 = *reinterpret_cast<const bf8_t*>(Qb + qbase);
  bf8_t qa1 = *reinterpret_cast<const bf8_t*>(Qb + qbase + 32);

  const int mBase = w * 256;
  // K chunk-tile base for this wave's first chunk (global chunk w*16)
  const size_t ktbase = ((size_t)((b * 128 + w * 16) * 16 + h)) << 10;
  const ushort* mpk = Mp + ((size_t)(b * 2048 + n0)) * 128 + (mBase >> 4);
  ushort* Ps = Pl + w * (16 * 256);  // this wave's strip

  // ---- pass 1: QK sweep, e -> LDS strip, accumulate l. Mask pre-loaded per 8-chunk half.
  float ls[4] = {0.f, 0.f, 0.f, 0.f};
#pragma unroll
  for (int g = 0; g < 2; ++g) {
    int4 mrow[4];
#pragma unroll
    for (int r = 0; r < 4; r++)
      mrow[r] = *reinterpret_cast<const int4*>(mpk + (size_t)(q * 4 + r) * 128 + g * 8);
#pragma unroll
    for (int mi = 0; mi < 8; ++mi) {
      const int mb = g * 8 + mi;
      const ushort* kp = Kt + ktbase + ((size_t)mb << 14) + dlo;  // tile stride 16<<10
      bf8_t k0 = *reinterpret_cast<const bf8_t*>(kp);
      bf8_t k1 = *reinterpret_cast<const bf8_t*>(kp + 512);
      f4_t s = (f4_t){0.f, 0.f, 0.f, 0.f};
      s = __builtin_amdgcn_mfma_f32_16x16x32_bf16(qa0, k0, s, 0, 0, 0);
      s = __builtin_amdgcn_mfma_f32_16x16x32_bf16(qa1, k1, s, 0, 0, 0);
      const int u = mb * 2 + (c >> 3);
#pragma unroll
      for (int reg = 0; reg < 4; reg++) {
        const int row = q * 4 + reg;
        unsigned mword = (unsigned)((mi >> 1) == 0 ? mrow[reg].x
                                  : (mi >> 1) == 1 ? mrow[reg].y
                                  : (mi >> 1) == 2 ? mrow[reg].z
                                                   : mrow[reg].w);
        unsigned masked = (mword >> ((mi & 1) * 16 + c)) & 1u;
        float e = masked ? 0.f : __builtin_amdgcn_exp2f(s[reg]);
        ls[reg] += e;
        Ps[row * 256 + (((u ^ (row & 7)) << 3) | (c & 7))] = f2b(e);
      }
    }
  }

  // ---- l reduce -> lpart
#pragma unroll
  for (int reg = 0; reg < 4; reg++) {
    ls[reg] += __shfl_xor(ls[reg], 1);
    ls[reg] += __shfl_xor(ls[reg], 2);
    ls[reg] += __shfl_xor(ls[reg], 4);
    ls[reg] += __shfl_xor(ls[reg], 8);
  }
  if (c == 0) {
#pragma unroll
    for (int reg = 0; reg < 4; reg++) lpart[w][q * 4 + reg] = ls[reg];
  }
  __syncthreads();  // P strips + lpart visible to all

  // ---- pass 2: PV (own strip, dense V tiles) interleaved with DENSE beta writes
  f4_t o[4];
#pragma unroll
  for (int db = 0; db < 4; db++) o[db] = (f4_t){0.f, 0.f, 0.f, 0.f};
  // V pv-tile base for this wave's first 32-chunk (mc = w*8)
  const size_t vtbase = ((size_t)((b * 16 + h) * 64 + w * 8)) << 11;

  const int br = 2 * w + (lane >> 5);
  const int j2 = lane & 31;
  float lsum_b = 0.f;
#pragma unroll
  for (int ww = 0; ww < 8; ww++) lsum_b += lpart[ww][br];
  const float li = 1.0f / lsum_b;
  float* brow = beta + ((size_t)(bh * 2048 + n0 + br)) * 2048;

#pragma unroll
  for (int p = 0; p < 8; ++p) {
    // PV part (own strip, dense 4KB tile = 4 x 1KB loads)
    const int u = p * 4 + q;
    bf8_t pa = *reinterpret_cast<const bf8_t*>(&Ps[c * 256 + ((u ^ (c & 7)) << 3)]);
    const ushort* vp = Vt + vtbase + ((size_t)p << 11) + dlo;
    __builtin_amdgcn_s_setprio(1);
#pragma unroll
    for (int db = 0; db < 4; db++) {
      bf8_t vf = *reinterpret_cast<const bf8_t*>(vp + db * 512);
      o[db] = __builtin_amdgcn_mfma_f32_16x16x32_bf16(pa, vf, o[db], 0, 0, 0);
    }
    __builtin_amdgcn_s_setprio(0);
    // beta part: 2 dense units (k = 2p, 2p+1), each 128 floats of row br
#pragma unroll
    for (int kk = 0; kk < 2; ++kk) {
      const int k = p * 2 + kk;
      const int s = k >> 1;                       // source strip
      const int off = (k & 1) * 128 + j2 * 4;     // col within strip
      const int uu = off >> 3;
      const int e4 = off & 7;                     // 0 or 4
      ushort4 pv4 = *reinterpret_cast<const ushort4*>(
          &Pl[s * 4096 + br * 256 + ((uu ^ (br & 7)) << 3) + e4]);
      float4 f;
      f.x = b2f(pv4.x) * li;
      f.y = b2f(pv4.y) * li;
      f.z = b2f(pv4.z) * li;
      f.w = b2f(pv4.w) * li;
      *reinterpret_cast<float4*>(brow + k * 128 + j2 * 4) = f;
    }
  }

  __syncthreads();  // all P reads done -> safe to overwrite with Ow

  // ---- merge O across 8 waves via union region, scale by 1/l, store concat bf16
#pragma unroll
  for (int db = 0; db < 4; db++)
#pragma unroll
    for (int reg = 0; reg < 4; reg++)
      OwU[(w * 16 + q * 4 + reg) * 68 + db * 16 + c] = o[db][reg];
  __syncthreads();
  if (t < 256) {
    int r = t >> 4;
    int d0 = (t & 15) * 4;
    float lsum = 0.f;
#pragma unroll
    for (int ww = 0; ww < 8; ww++) lsum += lpart[ww][r];
    float sl = 1.0f / lsum;
    float4 acc = (float4){0.f, 0.f, 0.f, 0.f};
#pragma unroll
    for (int ww = 0; ww < 8; ww++) {
      float4 sv = *reinterpret_cast<const float4*>(&OwU[(ww * 16 + r) * 68 + d0]);
      acc.x += sv.x; acc.y += sv.y; acc.z += sv.z; acc.w += sv.w;
    }
    ushort4 ov;
    ov.x = f2b(acc.x * sl);
    ov.y = f2b(acc.y * sl);
    ov.z = f2b(acc.z * sl);
    ov.w = f2b(acc.w * sl);
    *reinterpret_cast<ushort4*>(Cc + ((size_t)(b * 2048 + n0 + r)) * 1024 + h * 64 + d0) = ov;
  }
}

// ---------------------------------------------------------------- launch
extern "C" void kernel_launch(void* const* d_in, const int* in_sizes, int n_in,
                              void* d_out, int out_size, void* d_ws, size_t ws_size,
                              hipStream_t stream) {
  (void)in_sizes; (void)n_in; (void)out_size; (void)ws_size;
  const float* X = (const float*)d_in[0];
  const float* Y = (const float*)d_in[1];
  const int* mask = (const int*)d_in[2];
  const float* Wq = (const float*)d_in[3];
  const float* bq = (const float*)d_in[4];
  const float* Wk = (const float*)d_in[5];
  const float* bk = (const float*)d_in[6];
  const float* Wv = (const float*)d_in[7];
  const float* bv = (const float*)d_in[8];
  const float* Wo = (const float*)d_in[9];
  const float* bo = (const float*)d_in[10];
  float* out = (float*)d_out;

  const float SC = 0.18033688011112042f;  // (1/sqrt(64)) * log2(e), folded into Wq/bq

  char* ws = (char*)d_ws;
  const size_t SZ = 16777216;  // 8192*1024*2B
  ushort* Xb = (ushort*)(ws);
  ushort* Yb = (ushort*)(ws + SZ);
  ushort* Qb = (ushort*)(ws + 2 * SZ);
  ushort* Kb = (ushort*)(ws + 3 * SZ);   // K chunk-tiles
  ushort* Vt = (ushort*)(ws + 4 * SZ);   // V pv-tiles
  ushort* Cc = (ushort*)(ws + 5 * SZ);
  ushort* Wqb = (ushort*)(ws + 6 * SZ);
  ushort* Wkb = (ushort*)(ws + 6 * SZ + 2097152);
  ushort* Wvb = (ushort*)(ws + 6 * SZ + 2 * 2097152);
  ushort* Wob = (ushort*)(ws + 6 * SZ + 3 * 2097152);
  ushort* Mp  = (ushort*)(ws + 6 * SZ + 4 * 2097152);  // 2 MB packed mask

  cast_bf16_k<<<8192, 256, 0, stream>>>(X, Xb, 2097152, 1.0f);
  cast_bf16_k<<<8192, 256, 0, stream>>>(Y, Yb, 2097152, 1.0f);
  cast_bf16_k<<<1024, 256, 0, stream>>>(Wq, Wqb, 262144, SC);   // Q pre-scaled
  cast_bf16_k<<<1024, 256, 0, stream>>>(Wk, Wkb, 262144, 1.0f);
  cast_bf16_k<<<1024, 256, 0, stream>>>(Wv, Wvb, 262144, 1.0f);
  cast_bf16_k<<<1024, 256, 0, stream>>>(Wo, Wob, 262144, 1.0f);
  mask_pack_k<<<4096, 256, 0, stream>>>(mask, Mp, 1048576);

  gemm_bt<0><<<512, 256, 0, stream>>>(Xb, Wqb, bq, (void*)Qb, SC);
  gemm_bt<3><<<512, 256, 0, stream>>>(Yb, Wkb, bk, (void*)Kb, 1.0f);
  gemm_bt<4><<<512, 256, 0, stream>>>(Yb, Wvb, bv, (void*)Vt, 1.0f);

  attn_k<<<8192, 512, 0, stream>>>(Qb, Kb, Vt, Mp, out + 8388608, Cc);

  gemm_bt<2><<<512, 256, 0, stream>>>(Cc, Wob, bo, (void*)out, 1.0f);
}

// Round 14
// 553.402 us; speedup vs baseline: 1.6556x; 1.1050x over previous
//
#include <hip/hip_runtime.h>
#include <stdint.h>

typedef __attribute__((ext_vector_type(8))) short bf8_t;   // 8 bf16 (4 VGPRs) MFMA A/B frag
typedef __attribute__((ext_vector_type(4))) float f4_t;    // MFMA C/D frag

#define DEVI static __device__ __forceinline__

// fp32 -> bf16 round-to-nearest-even
DEVI unsigned short f2b(float f) {
  unsigned u = __builtin_bit_cast(unsigned, f);
  u += 0x7fffu + ((u >> 16) & 1u);
  return (unsigned short)(u >> 16);
}

DEVI float b2f(unsigned short v) {
  return __builtin_bit_cast(float, (unsigned)v << 16);
}

// LDS-only block barrier: drain own LDS ops, then raw s_barrier. Unlike __syncthreads,
// does NOT wait vmcnt(0) -> global loads/stores stay in flight across phase boundaries.
// Safe here: every barrier in attn_k protects only LDS state (P strips, lpart, Ow).
DEVI void block_sync_lds() {
  asm volatile("s_waitcnt lgkmcnt(0)" ::: "memory");
  __builtin_amdgcn_s_barrier();
}

// ---------------------------------------------------------------- fused cast kernels
__global__ void cast_xy_k(const float* __restrict__ X, const float* __restrict__ Y,
                          ushort* __restrict__ Xb, ushort* __restrict__ Yb) {
  int i = blockIdx.x * 256 + threadIdx.x;
  const float* s;
  ushort* d;
  int off;
  if (i < 2097152) { s = X; d = Xb; off = i; }
  else             { s = Y; d = Yb; off = i - 2097152; }
  float4 v = reinterpret_cast<const float4*>(s)[off];
  ushort4 o;
  o.x = f2b(v.x); o.y = f2b(v.y); o.z = f2b(v.z); o.w = f2b(v.w);
  reinterpret_cast<ushort4*>(d)[off] = o;
}

__global__ void cast_w_k(const float* __restrict__ Wq, const float* __restrict__ Wk,
                         const float* __restrict__ Wv, const float* __restrict__ Wo,
                         ushort* __restrict__ o0, ushort* __restrict__ o1,
                         ushort* __restrict__ o2, ushort* __restrict__ o3, float sc) {
  int i = blockIdx.x * 256 + threadIdx.x;
  int which = i >> 18;
  int off = i & 262143;
  const float* s = which == 0 ? Wq : which == 1 ? Wk : which == 2 ? Wv : Wo;
  ushort* d = which == 0 ? o0 : which == 1 ? o1 : which == 2 ? o2 : o3;
  float scale = which == 0 ? sc : 1.0f;
  float4 v = reinterpret_cast<const float4*>(s)[off];
  ushort4 o;
  o.x = f2b(v.x * scale); o.y = f2b(v.y * scale); o.z = f2b(v.z * scale); o.w = f2b(v.w * scale);
  reinterpret_cast<ushort4*>(d)[off] = o;
}

// ---------------------------------------------------------------- mask bit-pack
__global__ void mask_pack_k(const int* __restrict__ mask, ushort* __restrict__ mp, int nwords) {
  int i = blockIdx.x * 256 + threadIdx.x;
  if (i >= nwords) return;
  const int4* src = reinterpret_cast<const int4*>(mask + (size_t)i * 16);
  unsigned v = 0;
#pragma unroll
  for (int j = 0; j < 4; j++) {
    int4 m = src[j];
    v |= ((unsigned)(m.x & 1) << (j * 4 + 0));
    v |= ((unsigned)(m.y & 1) << (j * 4 + 1));
    v |= ((unsigned)(m.z & 1) << (j * 4 + 2));
    v |= ((unsigned)(m.w & 1) << (j * 4 + 3));
  }
  mp[i] = (ushort)v;
}

// ---------------------------------------------------------------- GEMM: C[n][o] = sum_d A[n][d]*W[o][d] + bias[o]*bscale
// MODE 0: out bf16 row-major (8192x1024)
// MODE 2: out fp32 row-major
// MODE 3: K chunk-tiles: Kt[((b*128+mb)*16+h)*1024 + s*512 + r*32 + c32] -> attn k0/k1 DENSE 1KB
// MODE 4: V pv-tiles:  Vt[((b*16+h)*64+mc)*2048 + d*32 + m32] -> attn V loads DENSE 1KB x4
template<int MODE>
__global__ __launch_bounds__(256, 3) void gemm_bt(const ushort* __restrict__ A,
                                                  const ushort* __restrict__ W,
                                                  const float* __restrict__ bias,
                                                  void* __restrict__ outp, float bscale) {
  __shared__ ushort As[128 * 64];
  __shared__ ushort Ws[128 * 64];
  const int t = threadIdx.x;
  const int tileCol = blockIdx.x & 7;
  const int tileRow = blockIdx.x >> 3;
  const int rowBase = tileRow * 128;
  const int colBase = tileCol * 128;

  const int r32 = t >> 3;
  const int cu = t & 7;
  const int w = t >> 6;
  const int lane = t & 63;
  const int q = lane >> 4;
  const int c = lane & 15;
  const int wr = (w >> 1) * 64;
  const int wc = (w & 1) * 64;

  f4_t acc[4][4];
#pragma unroll
  for (int i = 0; i < 4; i++)
#pragma unroll
    for (int j = 0; j < 4; j++) acc[i][j] = (f4_t){0.f, 0.f, 0.f, 0.f};

  for (int k0 = 0; k0 < 1024; k0 += 64) {
#pragma unroll
    for (int rs = 0; rs < 4; rs++) {
      int r = rs * 32 + r32;
      int4 va = *reinterpret_cast<const int4*>(A + (size_t)(rowBase + r) * 1024 + k0 + cu * 8);
      int4 vw = *reinterpret_cast<const int4*>(W + (size_t)(colBase + r) * 1024 + k0 + cu * 8);
      *reinterpret_cast<int4*>(&As[r * 64 + ((cu ^ (r & 7)) << 3)]) = va;
      *reinterpret_cast<int4*>(&Ws[r * 64 + ((cu ^ (r & 7)) << 3)]) = vw;
    }
    __syncthreads();
    bf8_t af[4][2], bfr[4][2];
#pragma unroll
    for (int i = 0; i < 4; i++) {
      int ra = wr + i * 16 + c;
      int rb = wc + i * 16 + c;
#pragma unroll
      for (int s = 0; s < 2; s++) {
        af[i][s] = *reinterpret_cast<const bf8_t*>(&As[ra * 64 + (((s * 4 + q) ^ (ra & 7)) << 3)]);
        bfr[i][s] = *reinterpret_cast<const bf8_t*>(&Ws[rb * 64 + (((s * 4 + q) ^ (rb & 7)) << 3)]);
      }
    }
#pragma unroll
    for (int i = 0; i < 4; i++)
#pragma unroll
      for (int j = 0; j < 4; j++) {
        acc[i][j] = __builtin_amdgcn_mfma_f32_16x16x32_bf16(af[i][0], bfr[j][0], acc[i][j], 0, 0, 0);
        acc[i][j] = __builtin_amdgcn_mfma_f32_16x16x32_bf16(af[i][1], bfr[j][1], acc[i][j], 0, 0, 0);
      }
    __syncthreads();
  }

  // epilogue: D layout col=lane&15, row=(lane>>4)*4+reg  [measured m89/m91]
#pragma unroll
  for (int j = 0; j < 4; j++) {
    int col = colBase + wc + j * 16 + c;
    float bj = bias[col] * bscale;
#pragma unroll
    for (int i = 0; i < 4; i++) {
      int rbase = rowBase + wr + i * 16 + q * 4;
      if (MODE == 0) {
        ushort* out = (ushort*)outp;
#pragma unroll
        for (int reg = 0; reg < 4; reg++)
          out[(size_t)(rbase + reg) * 1024 + col] = f2b(acc[i][j][reg] + bj);
      } else if (MODE == 2) {
        float* out = (float*)outp;
#pragma unroll
        for (int reg = 0; reg < 4; reg++)
          out[(size_t)(rbase + reg) * 1024 + col] = acc[i][j][reg] + bj;
      } else if (MODE == 3) {
        ushort* out = (ushort*)outp;
        const int bb = rbase >> 11;
        const int mb = (rbase >> 4) & 127;
        const int h = col >> 6;
        const int s = (col >> 5) & 1;
        const int c32 = col & 31;
        ushort* tb = out + (((size_t)(bb * 128 + mb) * 16 + h) << 10) + s * 512 + c32;
#pragma unroll
        for (int reg = 0; reg < 4; reg++)
          tb[(size_t)((q * 4 + reg) * 32)] = f2b(acc[i][j][reg] + bj);
      } else {
        ushort* out = (ushort*)outp;
        const int bb = rbase >> 11;
        const int mc = (rbase >> 5) & 63;
        const int m32 = rbase & 31;
        const int h = col >> 6;
        const int d = col & 63;
        ushort4 v;
        v.x = f2b(acc[i][j][0] + bj);
        v.y = f2b(acc[i][j][1] + bj);
        v.z = f2b(acc[i][j][2] + bj);
        v.w = f2b(acc[i][j][3] + bj);
        *reinterpret_cast<ushort4*>(out + ((((size_t)(bb * 16 + h) * 64 + mc) << 11) + d * 32 + m32)) = v;
      }
    }
  }
}

// ---------------------------------------------------------------- fused attention: P in LDS, dense K/V, no-vmcnt barriers
// Block: one (b,h), 16 q-rows, 512 threads; 8 waves x 256-col m-strips. Q PRE-SCALED by
// (1/sqrt(64))*log2(e).
// R14 changes on the R13 base (611 total):
//  (1) all 3 __syncthreads -> block_sync_lds (lgkmcnt(0)+raw s_barrier): __syncthreads also
//      drains vmcnt(0), serializing beta stores + any prefetched loads at every phase
//      boundary x 64 block-generations/SIMD. The barriers here protect LDS only.
//  (2) explicit 2-deep K prefetch (static 3-slot rotation) + both mask halves hoisted:
//      forces deep MLP in pass 1 instead of compiler's conservative depth.
//  (3) V double-buffer across the pass1->pass2 barrier: p=0's V issued BEFORE the barrier
//      (legal now that the barrier doesn't drain vmcnt), p+1 prefetched during p.
__global__ __launch_bounds__(512, 4) void attn_k(const ushort* __restrict__ Qb,
                                                 const ushort* __restrict__ Kt,
                                                 const ushort* __restrict__ Vt,
                                                 const ushort* __restrict__ Mp,
                                                 float* __restrict__ beta,
                                                 ushort* __restrict__ Cc) {
  __shared__ ushort Pl[8 * 16 * 256];  // 64KB: P strips [w][16 rows][256 cols], 16B-unit swizzled
  __shared__ float lpart[8][16];
  float* OwU = (float*)Pl;             // union: Ow[8][16][68] after P consumed

  const int L = blockIdx.x;
  const int bh = (L >> 10) * 8 + (L & 7);  // 0..63
  const int qt = (L >> 3) & 127;
  const int b = bh >> 4;
  const int h = bh & 15;
  const int n0 = qt * 16;

  const int t = threadIdx.x;
  const int w = t >> 6;    // 0..7
  const int lane = t & 63;
  const int q = lane >> 4;
  const int c = lane & 15;
  const int dlo = (c * 4 + q) * 8;  // dense lane offset: 64 lanes -> 1KB

  const size_t qbase = ((size_t)(b * 2048 + n0 + c)) * 1024 + h * 64 + q * 8;
  bf8_t qa0 = *reinterpret_cast<const bf8_t*>(Qb + qbase);
  bf8_t qa1 = *reinterpret_cast<const bf8_t*>(Qb + qbase + 32);

  const int mBase = w * 256;
  const size_t ktbase = ((size_t)((b * 128 + w * 16) * 16 + h)) << 10;
  const size_t vtbase = ((size_t)((b * 16 + h) * 64 + w * 8)) << 11;
  const ushort* mpk = Mp + ((size_t)(b * 2048 + n0)) * 128 + (mBase >> 4);
  ushort* Ps = Pl + w * (16 * 256);  // this wave's strip

  // ---- pass 1: QK sweep with 2-deep K prefetch; masks hoisted; e -> LDS strip; l accum
  float ls[4] = {0.f, 0.f, 0.f, 0.f};

  int4 mrow[2][4];
#pragma unroll
  for (int g = 0; g < 2; ++g)
#pragma unroll
    for (int r = 0; r < 4; r++)
      mrow[g][r] = *reinterpret_cast<const int4*>(mpk + (size_t)(q * 4 + r) * 128 + g * 8);

  bf8_t kpf[3][2];
  {
    const ushort* kp0 = Kt + ktbase + dlo;
    kpf[0][0] = *reinterpret_cast<const bf8_t*>(kp0);
    kpf[0][1] = *reinterpret_cast<const bf8_t*>(kp0 + 512);
    const ushort* kp1 = Kt + ktbase + (1 << 14) + dlo;
    kpf[1][0] = *reinterpret_cast<const bf8_t*>(kp1);
    kpf[1][1] = *reinterpret_cast<const bf8_t*>(kp1 + 512);
  }

#pragma unroll
  for (int mb = 0; mb < 16; ++mb) {
    if (mb < 14) {
      const ushort* kp = Kt + ktbase + ((size_t)(mb + 2) << 14) + dlo;
      kpf[(mb + 2) % 3][0] = *reinterpret_cast<const bf8_t*>(kp);
      kpf[(mb + 2) % 3][1] = *reinterpret_cast<const bf8_t*>(kp + 512);
    }
    f4_t s = (f4_t){0.f, 0.f, 0.f, 0.f};
    s = __builtin_amdgcn_mfma_f32_16x16x32_bf16(qa0, kpf[mb % 3][0], s, 0, 0, 0);
    s = __builtin_amdgcn_mfma_f32_16x16x32_bf16(qa1, kpf[mb % 3][1], s, 0, 0, 0);
    const int g = mb >> 3;
    const int mi = mb & 7;
    const int u = mb * 2 + (c >> 3);
#pragma unroll
    for (int reg = 0; reg < 4; reg++) {
      const int row = q * 4 + reg;
      unsigned mword = (unsigned)((mi >> 1) == 0 ? mrow[g][reg].x
                                : (mi >> 1) == 1 ? mrow[g][reg].y
                                : (mi >> 1) == 2 ? mrow[g][reg].z
                                                 : mrow[g][reg].w);
      unsigned masked = (mword >> ((mi & 1) * 16 + c)) & 1u;
      float e = masked ? 0.f : __builtin_amdgcn_exp2f(s[reg]);
      ls[reg] += e;
      Ps[row * 256 + (((u ^ (row & 7)) << 3) | (c & 7))] = f2b(e);
    }
  }

  // ---- issue V for p=0 BEFORE the barrier (stays in flight across it)
  bf8_t vpf[2][4];
  {
    const ushort* vp = Vt + vtbase + dlo;
#pragma unroll
    for (int db = 0; db < 4; db++) vpf[0][db] = *reinterpret_cast<const bf8_t*>(vp + db * 512);
  }

  // ---- l reduce -> lpart
#pragma unroll
  for (int reg = 0; reg < 4; reg++) {
    ls[reg] += __shfl_xor(ls[reg], 1);
    ls[reg] += __shfl_xor(ls[reg], 2);
    ls[reg] += __shfl_xor(ls[reg], 4);
    ls[reg] += __shfl_xor(ls[reg], 8);
  }
  if (c == 0) {
#pragma unroll
    for (int reg = 0; reg < 4; reg++) lpart[w][q * 4 + reg] = ls[reg];
  }
  block_sync_lds();  // P strips + lpart visible; V loads remain in flight

  // ---- pass 2: PV (dense V double-buffered) interleaved with DENSE beta writes
  f4_t o[4];
#pragma unroll
  for (int db = 0; db < 4; db++) o[db] = (f4_t){0.f, 0.f, 0.f, 0.f};

  const int br = 2 * w + (lane >> 5);
  const int j2 = lane & 31;
  float lsum_b = 0.f;
#pragma unroll
  for (int ww = 0; ww < 8; ww++) lsum_b += lpart[ww][br];
  const float li = 1.0f / lsum_b;
  float* brow = beta + ((size_t)(bh * 2048 + n0 + br)) * 2048;

#pragma unroll
  for (int p = 0; p < 8; ++p) {
    if (p < 7) {
      const ushort* vp = Vt + vtbase + ((size_t)(p + 1) << 11) + dlo;
#pragma unroll
      for (int db = 0; db < 4; db++)
        vpf[(p + 1) & 1][db] = *reinterpret_cast<const bf8_t*>(vp + db * 512);
    }
    const int u = p * 4 + q;
    bf8_t pa = *reinterpret_cast<const bf8_t*>(&Ps[c * 256 + ((u ^ (c & 7)) << 3)]);
    __builtin_amdgcn_s_setprio(1);
#pragma unroll
    for (int db = 0; db < 4; db++)
      o[db] = __builtin_amdgcn_mfma_f32_16x16x32_bf16(pa, vpf[p & 1][db], o[db], 0, 0, 0);
    __builtin_amdgcn_s_setprio(0);
    // beta: 2 dense units (k = 2p, 2p+1), each 128 floats of row br
#pragma unroll
    for (int kk = 0; kk < 2; ++kk) {
      const int k = p * 2 + kk;
      const int s = k >> 1;
      const int off = (k & 1) * 128 + j2 * 4;
      const int uu = off >> 3;
      const int e4 = off & 7;
      ushort4 pv4 = *reinterpret_cast<const ushort4*>(
          &Pl[s * 4096 + br * 256 + ((uu ^ (br & 7)) << 3) + e4]);
      float4 f;
      f.x = b2f(pv4.x) * li;
      f.y = b2f(pv4.y) * li;
      f.z = b2f(pv4.z) * li;
      f.w = b2f(pv4.w) * li;
      *reinterpret_cast<float4*>(brow + k * 128 + j2 * 4) = f;
    }
  }

  block_sync_lds();  // all P reads done -> safe to overwrite with Ow (beta stores still in flight)

  // ---- merge O across 8 waves via union region, scale by 1/l, store concat bf16
#pragma unroll
  for (int db = 0; db < 4; db++)
#pragma unroll
    for (int reg = 0; reg < 4; reg++)
      OwU[(w * 16 + q * 4 + reg) * 68 + db * 16 + c] = o[db][reg];
  block_sync_lds();
  if (t < 256) {
    int r = t >> 4;
    int d0 = (t & 15) * 4;
    float lsum = 0.f;
#pragma unroll
    for (int ww = 0; ww < 8; ww++) lsum += lpart[ww][r];
    float sl = 1.0f / lsum;
    float4 acc = (float4){0.f, 0.f, 0.f, 0.f};
#pragma unroll
    for (int ww = 0; ww < 8; ww++) {
      float4 sv = *reinterpret_cast<const float4*>(&OwU[(ww * 16 + r) * 68 + d0]);
      acc.x += sv.x; acc.y += sv.y; acc.z += sv.z; acc.w += sv.w;
    }
    ushort4 ov;
    ov.x = f2b(acc.x * sl);
    ov.y = f2b(acc.y * sl);
    ov.z = f2b(acc.z * sl);
    ov.w = f2b(acc.w * sl);
    *reinterpret_cast<ushort4*>(Cc + ((size_t)(b * 2048 + n0 + r)) * 1024 + h * 64 + d0) = ov;
  }
}

// ---------------------------------------------------------------- launch
extern "C" void kernel_launch(void* const* d_in, const int* in_sizes, int n_in,
                              void* d_out, int out_size, void* d_ws, size_t ws_size,
                              hipStream_t stream) {
  (void)in_sizes; (void)n_in; (void)out_size; (void)ws_size;
  const float* X = (const float*)d_in[0];
  const float* Y = (const float*)d_in[1];
  const int* mask = (const int*)d_in[2];
  const float* Wq = (const float*)d_in[3];
  const float* bq = (const float*)d_in[4];
  const float* Wk = (const float*)d_in[5];
  const float* bk = (const float*)d_in[6];
  const float* Wv = (const float*)d_in[7];
  const float* bv = (const float*)d_in[8];
  const float* Wo = (const float*)d_in[9];
  const float* bo = (const float*)d_in[10];
  float* out = (float*)d_out;

  const float SC = 0.18033688011112042f;  // (1/sqrt(64)) * log2(e), folded into Wq/bq

  char* ws = (char*)d_ws;
  const size_t SZ = 16777216;  // 8192*1024*2B
  ushort* Xb = (ushort*)(ws);
  ushort* Yb = (ushort*)(ws + SZ);
  ushort* Qb = (ushort*)(ws + 2 * SZ);
  ushort* Kb = (ushort*)(ws + 3 * SZ);   // K chunk-tiles
  ushort* Vt = (ushort*)(ws + 4 * SZ);   // V pv-tiles
  ushort* Cc = (ushort*)(ws + 5 * SZ);
  ushort* Wqb = (ushort*)(ws + 6 * SZ);
  ushort* Wkb = (ushort*)(ws + 6 * SZ + 2097152);
  ushort* Wvb = (ushort*)(ws + 6 * SZ + 2 * 2097152);
  ushort* Wob = (ushort*)(ws + 6 * SZ + 3 * 2097152);
  ushort* Mp  = (ushort*)(ws + 6 * SZ + 4 * 2097152);  // 2 MB packed mask

  cast_xy_k<<<16384, 256, 0, stream>>>(X, Y, Xb, Yb);
  cast_w_k<<<4096, 256, 0, stream>>>(Wq, Wk, Wv, Wo, Wqb, Wkb, Wvb, Wob, SC);
  mask_pack_k<<<4096, 256, 0, stream>>>(mask, Mp, 1048576);

  gemm_bt<0><<<512, 256, 0, stream>>>(Xb, Wqb, bq, (void*)Qb, SC);
  gemm_bt<3><<<512, 256, 0, stream>>>(Yb, Wkb, bk, (void*)Kb, 1.0f);
  gemm_bt<4><<<512, 256, 0, stream>>>(Yb, Wvb, bv, (void*)Vt, 1.0f);

  attn_k<<<8192, 512, 0, stream>>>(Qb, Kb, Vt, Mp, out + 8388608, Cc);

  gemm_bt<2><<<512, 256, 0, stream>>>(Cc, Wob, bo, (void*)out, 1.0f);
}